// Round 4
// baseline (95.902 us; speedup 1.0000x reference)
//
#include <hip/hip_runtime.h>

// HarmonicConvolutionFilter on MI355X (round 4 = round 3 + compile fix).
// x: [B=4, S=1024, F=512, C=4] f32;  W: [5, K=4, C=4, O=4] f32;  out: [B,S,F,4] f32
// out[b,s,f,o] = sum_t sum_k sum_c x_pad[b,s+t-2, f*(k+1), c] * W[t,k,c,o], k masked if f*(k+1)>=F
//
// Round-3 theory (unchanged): kernel was ~31us at occupancy 27% with no
// throughput pipe near its ceiling -> L2-latency-bound at 4 waves/SIMD.
//  1. TS 4 -> 2: grid 2048 blocks = 8 blocks/CU = 8 waves/SIMD (full occ).
//  2. __launch_bounds__(256,8) caps VGPR at 64.
//  3. Non-temporal output stores (write-once) -- via clang ext_vector_type
//     alias, since __builtin_nontemporal_store rejects HIP_vector_type.

#define TS    2      // time strip per thread
#define NTAP  5
#define FB    512
#define SB    1024
#define BB    4

typedef float vfloat4 __attribute__((ext_vector_type(4)));

__device__ __forceinline__ void nt_store4(float4 v, float4* p) {
    vfloat4 raw = { v.x, v.y, v.z, v.w };
    __builtin_nontemporal_store(raw, (vfloat4*)p);
}

__global__ __launch_bounds__(256, 8)
void harmonic_conv_kernel(const float* __restrict__ x,
                          const float* __restrict__ W,
                          float* __restrict__ out) {
    // grid: BB * (SB/TS) = 2048 blocks of 256 threads
    const int bid  = blockIdx.x;
    const int work = ((bid & 7) << 8) + (bid >> 3);   // XCD-contiguous chunks
    const int b    = work >> 9;                       // 0..3  (512 strips per b)
    const int s0   = (work & 511) * TS;               // 0..1022
    const int tid  = threadIdx.x;

    const float4* xb = (const float4*)x + (size_t)b * SB * FB;
    float4*       ob = (float4*)out + (size_t)b * SB * FB;

    // ---------- high half: f = tid + 256, only harmonic m=1 valid ----------
    {
        const int g = tid + 256;
        float4 xw[TS + 4];
#pragma unroll
        for (int r = 0; r < TS + 4; ++r) {
            const int sp = s0 + r - 2;                // block-uniform predicate
            xw[r] = (sp >= 0 && sp < SB) ? xb[(size_t)sp * FB + g]
                                         : make_float4(0.f, 0.f, 0.f, 0.f);
        }
        float4 acc[TS];
#pragma unroll
        for (int j = 0; j < TS; ++j) acc[j] = make_float4(0.f, 0.f, 0.f, 0.f);
#pragma unroll
        for (int t = 0; t < NTAP; ++t) {
            const float* wp = W + t * 64;             // k=0; uniform -> s_load
            float w[16];
#pragma unroll
            for (int i = 0; i < 16; ++i) w[i] = wp[i];
#pragma unroll
            for (int j = 0; j < TS; ++j) {
                const float4 xv = xw[j + t];
                acc[j].x += xv.x*w[0] + xv.y*w[4] + xv.z*w[8]  + xv.w*w[12];
                acc[j].y += xv.x*w[1] + xv.y*w[5] + xv.z*w[9]  + xv.w*w[13];
                acc[j].z += xv.x*w[2] + xv.y*w[6] + xv.z*w[10] + xv.w*w[14];
                acc[j].w += xv.x*w[3] + xv.y*w[7] + xv.z*w[11] + xv.w*w[15];
            }
        }
#pragma unroll
        for (int j = 0; j < TS; ++j)
            nt_store4(acc[j], &ob[(size_t)(s0 + j) * FB + g]);
    }

    // ---------- low half: f = tid (0..255), harmonics m=1..4 ----------
    {
        const int f = tid;
        float4 acc[TS];
#pragma unroll
        for (int j = 0; j < TS; ++j) acc[j] = make_float4(0.f, 0.f, 0.f, 0.f);

#pragma unroll
        for (int m = 1; m <= 4; ++m) {
            const int g = f * m;
            if (g < FB) {                             // m=1,2 always true here
                float4 xw[TS + 4];
#pragma unroll
                for (int r = 0; r < TS + 4; ++r) {
                    const int sp = s0 + r - 2;
                    xw[r] = (sp >= 0 && sp < SB) ? xb[(size_t)sp * FB + g]
                                                 : make_float4(0.f, 0.f, 0.f, 0.f);
                }
#pragma unroll
                for (int t = 0; t < NTAP; ++t) {
                    const float* wp = W + t * 64 + (m - 1) * 16;
                    float w[16];
#pragma unroll
                    for (int i = 0; i < 16; ++i) w[i] = wp[i];
#pragma unroll
                    for (int j = 0; j < TS; ++j) {
                        const float4 xv = xw[j + t];
                        acc[j].x += xv.x*w[0] + xv.y*w[4] + xv.z*w[8]  + xv.w*w[12];
                        acc[j].y += xv.x*w[1] + xv.y*w[5] + xv.z*w[9]  + xv.w*w[13];
                        acc[j].z += xv.x*w[2] + xv.y*w[6] + xv.z*w[10] + xv.w*w[14];
                        acc[j].w += xv.x*w[3] + xv.y*w[7] + xv.z*w[11] + xv.w*w[15];
                    }
                }
            }
        }
#pragma unroll
        for (int j = 0; j < TS; ++j)
            nt_store4(acc[j], &ob[(size_t)(s0 + j) * FB + f]);
    }
}

extern "C" void kernel_launch(void* const* d_in, const int* in_sizes, int n_in,
                              void* d_out, int out_size, void* d_ws, size_t ws_size,
                              hipStream_t stream) {
    const float* x = (const float*)d_in[0];
    const float* W = (const float*)d_in[1];
    float* out = (float*)d_out;
    const int nblocks = BB * (SB / TS);   // 2048
    harmonic_conv_kernel<<<nblocks, 256, 0, stream>>>(x, W, out);
}

// Round 6
// 94.932 us; speedup vs baseline: 1.0102x; 1.0102x over previous
//
#include <hip/hip_runtime.h>

// HarmonicConvolutionFilter on MI355X (round 6 = round 5 resubmit; GPU timeout).
// x: [B=4, S=1024, F=512, C=4] f32;  W: [5, K=4, C=4, O=4] f32;  out: [B,S,F,4] f32
// out[b,s,f,o] = sum_t sum_k sum_c x_pad[b,s+t-2, f*(k+1), c] * W[t,k,c,o], k masked if f*(k+1)>=F
//
// Round-4 post-mortem: occupancy 2x (4->8 waves/SIMD) changed NOTHING ->
// not TLP-starved. Theory: block read footprint 48KB > 32KB L1, so all ~25
// loads/thread are L2 round-trips, and the stride-m harmonic gathers split
// into 2-4x 128B segments -> per-CU memory request queue saturates.
// Round-5: stage the block's 6 rows x 512 f into LDS ONCE (12 coalesced
// float4/thread), then ALL harmonic/tap reads are ds_read_b128 from LDS.
// Pad-every-16 swizzle (idx = f + f/16) keeps stride-2/3/4 gathers at ~2x
// phase conflict instead of 8-way. LDS 51KB -> 3 blocks/CU.

#define TS    2      // time strip per thread
#define NTAP  5
#define FB    512
#define SB    1024
#define BB    4
#define NROW  (TS + 4)          // 6 rows staged (TS + 2*halo)
#define ROWP  544               // 512 + 32 pad slots (one per 16), float4 units

typedef float vfloat4 __attribute__((ext_vector_type(4)));

__device__ __forceinline__ void nt_store4(float4 v, float4* p) {
    vfloat4 raw = { v.x, v.y, v.z, v.w };
    __builtin_nontemporal_store(raw, (vfloat4*)p);
}

__device__ __forceinline__ int swz(int f) { return f + (f >> 4); }

// accumulate harmonic with weights Wk = W + (m-1)*16, source column g = f*m
__device__ __forceinline__ void accum_harm(const float4* lx, int g,
                                           const float* __restrict__ Wk,
                                           float4 acc[TS]) {
    float4 xw[NROW];
#pragma unroll
    for (int r = 0; r < NROW; ++r) xw[r] = lx[r * ROWP + swz(g)];
#pragma unroll
    for (int t = 0; t < NTAP; ++t) {
        const float* wp = Wk + t * 64;   // uniform address -> s_load
        float w[16];
#pragma unroll
        for (int i = 0; i < 16; ++i) w[i] = wp[i];
#pragma unroll
        for (int j = 0; j < TS; ++j) {
            const float4 xv = xw[j + t];
            acc[j].x += xv.x*w[0] + xv.y*w[4] + xv.z*w[8]  + xv.w*w[12];
            acc[j].y += xv.x*w[1] + xv.y*w[5] + xv.z*w[9]  + xv.w*w[13];
            acc[j].z += xv.x*w[2] + xv.y*w[6] + xv.z*w[10] + xv.w*w[14];
            acc[j].w += xv.x*w[3] + xv.y*w[7] + xv.z*w[11] + xv.w*w[15];
        }
    }
}

__global__ __launch_bounds__(256, 3)
void harmonic_conv_kernel(const float* __restrict__ x,
                          const float* __restrict__ W,
                          float* __restrict__ out) {
    __shared__ float4 lx[NROW * ROWP];   // 6*544*16B = 51KB

    // grid: BB * (SB/TS) = 2048 blocks of 256 threads
    const int bid  = blockIdx.x;
    const int work = ((bid & 7) << 8) | (bid >> 3);   // XCD-contiguous chunks
    const int b    = work >> 9;                       // 0..3
    const int s0   = (work & 511) * TS;               // 0..1022
    const int tid  = threadIdx.x;

    const float4* xb = (const float4*)x + (size_t)b * SB * FB;
    float4*       ob = (float4*)out + (size_t)b * SB * FB;

    // ---- stage 6 rows x 512 f (coalesced); pad rows -> 0 ----
#pragma unroll
    for (int i = 0; i < NROW * FB / 256; ++i) {       // 12 iters
        const int n  = i * 256 + tid;
        const int r  = n >> 9;                        // uniform per iter
        const int f  = n & (FB - 1);
        const int sp = s0 + r - 2;                    // uniform predicate
        float4 v = make_float4(0.f, 0.f, 0.f, 0.f);
        if (sp >= 0 && sp < SB) v = xb[(size_t)sp * FB + f];
        lx[r * ROWP + swz(f)] = v;
    }
    __syncthreads();

    float4 acc[TS];

    // ---- high half: f = tid + 256, only m=1 valid ----
#pragma unroll
    for (int j = 0; j < TS; ++j) acc[j] = make_float4(0.f, 0.f, 0.f, 0.f);
    accum_harm(lx, tid + 256, W, acc);
#pragma unroll
    for (int j = 0; j < TS; ++j)
        nt_store4(acc[j], &ob[(size_t)(s0 + j) * FB + (tid + 256)]);

    // ---- low half: f = tid, harmonics m=1..4 ----
#pragma unroll
    for (int j = 0; j < TS; ++j) acc[j] = make_float4(0.f, 0.f, 0.f, 0.f);
    accum_harm(lx, tid,     W,      acc);             // m=1 (always valid)
    accum_harm(lx, tid * 2, W + 16, acc);             // m=2 (always valid)
    if (tid * 3 < FB) accum_harm(lx, tid * 3, W + 32, acc);   // m=3: f<171
    if (tid * 4 < FB) accum_harm(lx, tid * 4, W + 48, acc);   // m=4: f<128
#pragma unroll
    for (int j = 0; j < TS; ++j)
        nt_store4(acc[j], &ob[(size_t)(s0 + j) * FB + tid]);
}

extern "C" void kernel_launch(void* const* d_in, const int* in_sizes, int n_in,
                              void* d_out, int out_size, void* d_ws, size_t ws_size,
                              hipStream_t stream) {
    const float* x = (const float*)d_in[0];
    const float* W = (const float*)d_in[1];
    float* out = (float*)d_out;
    const int nblocks = BB * (SB / TS);   // 2048
    harmonic_conv_kernel<<<nblocks, 256, 0, stream>>>(x, W, out);
}

// Round 7
// 93.455 us; speedup vs baseline: 1.0262x; 1.0158x over previous
//
#include <hip/hip_runtime.h>

// HarmonicConvolutionFilter on MI355X (round 7).
// x: [B=4, S=1024, F=512, C=4] f32;  W: [5, K=4, C=4, O=4] f32;  out: [B,S,F,4] f32
// out[b,s,f,o] = sum_t sum_k sum_c x_pad[b,s+t-2, f*(k+1), c] * W[t,k,c,o], k masked if f*(k+1)>=F
//
// Rounds 4/6 post-mortem: occupancy 2x AND LDS staging both NULL; three
// different kernels all ~31us. Best fit: HBM-bound on REDUNDANT traffic
// (127MB fetch + 33MB write at ~5.2TB/s = 31us) because cross-block L2 reuse
// never happened (XCD mapping assumption unverified). Round 2's 2x came from
// load BALANCE, not the swizzle.
// Round-7: rolling-window s-loop. Block = (b, s-chunk of 8) x all 512 f.
// 8-slot LDS row ring (64KB, 2 blocks/CU): prologue stages 6 rows; each
// 2-row step stages 2 new rows (global loads issued BEFORE compute, ds_write
// after = T14 async-split). Read amp = 12rows/8outputs = 1.5x with ZERO
// reliance on inter-block caching -> FETCH ~50MB by construction.
// Pad-free XOR swizzle f^((f>>4)&7) spreads stride-1/2/3/4 LDS gathers
// uniformly over bank-groups (residue-enumerated for all m).

#define SC    8      // s-chunk per block (outputs)
#define NSLOT 8      // LDS row ring slots
#define NTAP  5
#define FB    512
#define SB    1024
#define BB    4
#define ROWP  512    // float4 per row slot (no pad; XOR swizzle instead)

__device__ __forceinline__ int swz(int f) { return f ^ ((f >> 4) & 7); }

// accumulate one harmonic: source column g across the 6-row window.
// slotbase[r] = float4-offset of LDS slot holding row (s0 + r - 2), r=0..5
__device__ __forceinline__ void accum_harm(const float4* lx, const int* slotbase,
                                           int g, const float* __restrict__ Wk,
                                           float4 acc[2]) {
    float4 xw[6];
#pragma unroll
    for (int r = 0; r < 6; ++r) xw[r] = lx[slotbase[r] + swz(g)];
#pragma unroll
    for (int t = 0; t < NTAP; ++t) {
        const float* wp = Wk + t * 64;   // uniform address -> scalar loads
        float w[16];
#pragma unroll
        for (int i = 0; i < 16; ++i) w[i] = wp[i];
#pragma unroll
        for (int j = 0; j < 2; ++j) {
            const float4 xv = xw[j + t];
            acc[j].x += xv.x*w[0] + xv.y*w[4] + xv.z*w[8]  + xv.w*w[12];
            acc[j].y += xv.x*w[1] + xv.y*w[5] + xv.z*w[9]  + xv.w*w[13];
            acc[j].z += xv.x*w[2] + xv.y*w[6] + xv.z*w[10] + xv.w*w[14];
            acc[j].w += xv.x*w[3] + xv.y*w[7] + xv.z*w[11] + xv.w*w[15];
        }
    }
}

__global__ __launch_bounds__(256, 2)
void harmonic_conv_kernel(const float* __restrict__ x,
                          const float* __restrict__ W,
                          float* __restrict__ out) {
    __shared__ float4 lx[NSLOT * ROWP];   // 8 * 512 * 16B = 64 KB

    // grid: BB * (SB/SC) = 512 blocks of 256 threads
    const int bid = blockIdx.x;
    const int b   = bid >> 7;             // 0..3
    const int c   = (bid & 127) * SC;     // chunk start s, multiple of 8
    const int tid = threadIdx.x;

    const float4* xb = (const float4*)x + (size_t)b * SB * FB;
    float4*       ob = (float4*)out + (size_t)b * SB * FB;

    // slot(R) = (R - c + 2) & 7.  Prologue: rows c-2..c+3 -> slots 0..5.
#pragma unroll
    for (int r = 0; r < 6; ++r) {
        const int sp = c - 2 + r;
#pragma unroll
        for (int h = 0; h < 2; ++h) {
            const int col = h * 256 + tid;
            float4 v = make_float4(0.f, 0.f, 0.f, 0.f);
            if (sp >= 0 && sp < SB) v = xb[(size_t)sp * FB + col];
            lx[r * ROWP + swz(col)] = v;
        }
    }
    __syncthreads();

#pragma unroll 1
    for (int st = 0; st < SC; st += 2) {
        // ---- issue staging loads EARLY (rows c+st+4, c+st+5) ----
        float4 sv[4];
        const bool do_stage = (st < SC - 2);   // block-uniform
        if (do_stage) {
            const int r0 = c + st + 4, r1 = c + st + 5;
#pragma unroll
            for (int h = 0; h < 2; ++h) {
                sv[h]     = (r0 < SB) ? xb[(size_t)r0 * FB + h * 256 + tid]
                                      : make_float4(0.f, 0.f, 0.f, 0.f);
                sv[2 + h] = (r1 < SB) ? xb[(size_t)r1 * FB + h * 256 + tid]
                                      : make_float4(0.f, 0.f, 0.f, 0.f);
            }
        }

        // ---- compute outputs s = c+st, c+st+1 from slots (st..st+5)&7 ----
        int slotbase[6];
#pragma unroll
        for (int r = 0; r < 6; ++r) slotbase[r] = ((st + r) & 7) * ROWP;

        float4 acc[2];

        // high half: f = tid + 256, m=1 only
        acc[0] = make_float4(0.f, 0.f, 0.f, 0.f);
        acc[1] = make_float4(0.f, 0.f, 0.f, 0.f);
        accum_harm(lx, slotbase, tid + 256, W, acc);
#pragma unroll
        for (int j = 0; j < 2; ++j)
            ob[(size_t)(c + st + j) * FB + (tid + 256)] = acc[j];

        // low half: f = tid, m = 1..4
        acc[0] = make_float4(0.f, 0.f, 0.f, 0.f);
        acc[1] = make_float4(0.f, 0.f, 0.f, 0.f);
        accum_harm(lx, slotbase, tid,     W,      acc);            // m=1
        accum_harm(lx, slotbase, tid * 2, W + 16, acc);            // m=2
        if (tid * 3 < FB) accum_harm(lx, slotbase, tid * 3, W + 32, acc);
        if (tid * 4 < FB) accum_harm(lx, slotbase, tid * 4, W + 48, acc);
#pragma unroll
        for (int j = 0; j < 2; ++j)
            ob[(size_t)(c + st + j) * FB + tid] = acc[j];

        // ---- LATE write of staged rows into ring slots (st+6,st+7)&7 ----
        if (do_stage) {
#pragma unroll
            for (int h = 0; h < 2; ++h) {
                lx[((st + 6) & 7) * ROWP + swz(h * 256 + tid)] = sv[h];
                lx[((st + 7) & 7) * ROWP + swz(h * 256 + tid)] = sv[2 + h];
            }
        }
        __syncthreads();
    }
}

extern "C" void kernel_launch(void* const* d_in, const int* in_sizes, int n_in,
                              void* d_out, int out_size, void* d_ws, size_t ws_size,
                              hipStream_t stream) {
    const float* x = (const float*)d_in[0];
    const float* W = (const float*)d_in[1];
    float* out = (float*)d_out;
    const int nblocks = BB * (SB / SC);   // 512
    harmonic_conv_kernel<<<nblocks, 256, 0, stream>>>(x, W, out);
}